// Round 1
// baseline (99681.433 us; speedup 1.0000x reference)
//
#include <hip/hip_runtime.h>
#include <hip/hip_cooperative_groups.h>

namespace cg = cooperative_groups;

constexpr int kH = 1024;   // hidden
constexpr int kT = 512;    // encoder steps
constexpr int kP = 96;     // decoder steps
constexpr int kB = 256;    // batch
constexpr int kSteps = kT + kP;

__device__ __forceinline__ float sig_(float x) { return 1.0f / (1.0f + __expf(-x)); }
__device__ __forceinline__ float tanh_(float x) {
  float e = __expf(-2.0f * fabsf(x));
  float t = (1.0f - e) / (1.0f + e);
  return copysignf(t, x);
}

// Persistent cooperative kernel.
// grid = 256 blocks (block bid owns hidden units j0=4*bid..j0+3 -> 16 gate rows)
// block = 512 threads: b = tid&255 (batch), half = tid>>8 (k-half of the dot)
// h stored TRANSPOSED hT[k][b] (ping/pong in ws) so reads+writes are coalesced.
__global__ void __launch_bounds__(512, 1)
lstm_s2s(const float* __restrict__ xin,   // [B][T]
         const float* __restrict__ eWih,  // [4H]
         const float* __restrict__ eWhh,  // [4H][H]
         const float* __restrict__ eb,    // [4H]
         const float* __restrict__ h0,    // [H]
         const float* __restrict__ c0,    // [H]
         const float* __restrict__ dWih,
         const float* __restrict__ dWhh,
         const float* __restrict__ db,
         const float* __restrict__ outW,  // [H]
         const float* __restrict__ outb,  // [1]
         float* __restrict__ out,         // [B][P]
         float* __restrict__ hApg,        // ws: hT ping [H][B]
         float* __restrict__ hBpg,        // ws: hT pong [H][B]
         float* __restrict__ decin)       // ws: [B]
{
  cg::grid_group grid = cg::this_grid();
  const int tid  = threadIdx.x;
  const int b    = tid & 255;
  const int half = tid >> 8;
  const int bid  = blockIdx.x;
  const int j0   = bid * 4;

  __shared__ float red[256][17];   // +1 pad -> conflict-free
  __shared__ float red2[8];

  float c[4] = {0.f, 0.f, 0.f, 0.f};
  if (half == 0) {
#pragma unroll
    for (int q = 0; q < 4; ++q) {
      hApg[(j0 + q) * kB + b] = h0[j0 + q];
      c[q] = c0[j0 + q];
    }
  }
  grid.sync();

  float* hc = hApg;
  float* hn = hBpg;

  for (int step = 0; step < kSteps; ++step) {
    const bool dec = (step >= kT);
    const float* __restrict__ Wih  = dec ? dWih : eWih;
    const float* __restrict__ Whh  = dec ? dWhh : eWhh;
    const float* __restrict__ bias = dec ? db   : eb;

    float acc[16];
    if (half == 0) {
      float xv;
      if (!dec)             xv = xin[b * kT + step];
      else if (step == kT)  xv = xin[b * kT + (kT - 1)];
      else                  xv = decin[b];
#pragma unroll
      for (int g = 0; g < 4; ++g)
#pragma unroll
        for (int q = 0; q < 4; ++q) {
          int r = g * kH + j0 + q;
          acc[g * 4 + q] = bias[r] + xv * Wih[r];
        }
    } else {
#pragma unroll
      for (int i = 0; i < 16; ++i) acc[i] = 0.0f;
    }

    // gates[b][r] += sum_k h[b][k] * Whh[r][k]  over this thread's k-half.
    // Whh row addresses are wave-uniform -> scalar loads; h reads coalesced.
    const int k0 = half * (kH / 2);
#pragma unroll 4
    for (int k = k0; k < k0 + kH / 2; ++k) {
      float hv = hc[k * kB + b];
#pragma unroll
      for (int g = 0; g < 4; ++g)
#pragma unroll
        for (int q = 0; q < 4; ++q)
          acc[g * 4 + q] = fmaf(Whh[(g * kH + j0 + q) * kH + k], hv, acc[g * 4 + q]);
    }

    // combine the two k-halves through LDS
    if (half == 1) {
#pragma unroll
      for (int i = 0; i < 16; ++i) red[b][i] = acc[i];
    }
    __syncthreads();
    if (half == 0) {
#pragma unroll
      for (int i = 0; i < 16; ++i) acc[i] += red[b][i];
      float hnew[4];
#pragma unroll
      for (int q = 0; q < 4; ++q) {
        float ig = sig_(acc[0 + q]);
        float fg = sig_(acc[4 + q]);
        float gg = tanh_(acc[8 + q]);
        float og = sig_(acc[12 + q]);
        c[q] = fg * c[q] + ig * gg;
        hnew[q] = og * tanh_(c[q]);
      }
#pragma unroll
      for (int q = 0; q < 4; ++q)
        hn[(j0 + q) * kB + b] = hnew[q];   // coalesced across lanes
    }
    grid.sync();

    if (dec) {
      // out[b'] = dot(h[b'], outW) + outb ; block bid handles batch b'=bid.
      float part = 0.0f;
#pragma unroll
      for (int u = 0; u < 2; ++u) {
        int k = tid * 2 + u;
        part = fmaf(hn[k * kB + bid], outW[k], part);
      }
#pragma unroll
      for (int off = 32; off > 0; off >>= 1)
        part += __shfl_down(part, off, 64);
      if ((tid & 63) == 0) red2[tid >> 6] = part;
      __syncthreads();
      if (tid == 0) {
        float tot = outb[0];
#pragma unroll
        for (int w = 0; w < 8; ++w) tot += red2[w];
        out[bid * kP + (step - kT)] = tot;
        decin[bid] = tot;   // autoregressive feedback
      }
      grid.sync();
    }

    float* tmp = hc; hc = hn; hn = tmp;
  }
}

extern "C" void kernel_launch(void* const* d_in, const int* in_sizes, int n_in,
                              void* d_out, int out_size, void* d_ws, size_t ws_size,
                              hipStream_t stream) {
  const float* xin  = (const float*)d_in[0];
  const float* eWih = (const float*)d_in[1];
  const float* eWhh = (const float*)d_in[2];
  const float* eb   = (const float*)d_in[3];
  const float* h0   = (const float*)d_in[4];
  const float* c0   = (const float*)d_in[5];
  const float* dWih = (const float*)d_in[6];
  const float* dWhh = (const float*)d_in[7];
  const float* db   = (const float*)d_in[8];
  const float* outW = (const float*)d_in[9];
  const float* outb = (const float*)d_in[10];
  float* out = (float*)d_out;

  float* wsf   = (float*)d_ws;
  float* hApg  = wsf;                 // 1024*256
  float* hBpg  = wsf + kH * kB;       // 1024*256
  float* decin = wsf + 2 * kH * kB;   // 256

  void* args[] = {(void*)&xin, (void*)&eWih, (void*)&eWhh, (void*)&eb,
                  (void*)&h0, (void*)&c0, (void*)&dWih, (void*)&dWhh,
                  (void*)&db, (void*)&outW, (void*)&outb,
                  (void*)&out, (void*)&hApg, (void*)&hBpg, (void*)&decin};
  hipLaunchCooperativeKernel((const void*)lstm_s2s, dim3(256), dim3(512),
                             args, 0, stream);
}

// Round 3
// 87944.452 us; speedup vs baseline: 1.1335x; 1.1335x over previous
//
#include <hip/hip_runtime.h>
#include <hip/hip_cooperative_groups.h>

namespace cg = cooperative_groups;

constexpr int kH = 1024;   // hidden
constexpr int kT = 512;    // encoder steps
constexpr int kP = 96;     // decoder steps
constexpr int kB = 256;    // batch
constexpr int kSteps = kT + kP;
constexpr int ROWS = 16;   // 4 hidden units * 4 gates per block

__device__ __forceinline__ float sig_(float x) { return 1.0f / (1.0f + __expf(-x)); }
__device__ __forceinline__ float tanh_(float x) {
  float e = __expf(-2.0f * fabsf(x));
  float t = (1.0f - e) / (1.0f + e);
  return copysignf(t, x);
}

// grid = 256 blocks x 1024 threads (16 waves/CU = 4/SIMD).
// Block bid owns hidden units j0..j0+3 -> 16 gate rows, Whh slice in LDS (64KB).
// k-loop: wave w handles k-slice [64w,64w+64); lane=batch base, 4 batches/thread.
// Cell update: thread tid -> (jj = tid>>8 hidden unit, bb = tid&255 batch).
__global__ void __launch_bounds__(1024, 4)
lstm2(const float* __restrict__ xin,   // [B][T]
      const float* __restrict__ eWih,  // [4H]
      const float* __restrict__ eWhh,  // [4H][H]
      const float* __restrict__ eb,    // [4H]
      const float* __restrict__ h0,    // [H]
      const float* __restrict__ c0,    // [H]
      const float* __restrict__ dWih,
      const float* __restrict__ dWhh,
      const float* __restrict__ db,
      const float* __restrict__ outW,  // [H]
      const float* __restrict__ outb,  // [1]
      float* __restrict__ out,         // [B][P]
      float* __restrict__ hA,          // ws: hT ping [H][B]
      float* __restrict__ hB,          // ws: hT pong [H][B]
      float* __restrict__ xT,          // ws: [T][B]
      float* __restrict__ decin,       // ws: [B]
      float* __restrict__ decacc)      // ws: [2][B]
{
  cg::grid_group grid = cg::this_grid();
  const int tid  = threadIdx.x;
  const int bid  = blockIdx.x;
  const int j0   = bid * 4;
  const int lane = tid & 63;
  const int wv   = tid >> 6;   // 0..15 : k-slice
  const int jj   = tid >> 8;   // 0..3  : hidden unit (update phase)
  const int bb   = tid & 255;  //        batch (update phase)

  __shared__ float Wl[ROWS * kH];     // 64 KB  weight slice [r][k]
  __shared__ float gsum[ROWS * kB];   // 16 KB  gate partial sums [r][b]

  // ---- one-time init ------------------------------------------------------
#pragma unroll
  for (int lr = 0; lr < ROWS; ++lr)   // stage encoder Whh slice (coalesced)
    Wl[lr * kH + tid] = eWhh[(((lr >> 2) * kH) + j0 + (lr & 3)) * kH + tid];

  ((float4*)gsum)[tid] = make_float4(0.f, 0.f, 0.f, 0.f);

  hA[(j0 + jj) * kB + bb] = h0[j0 + jj];
  float cReg    = c0[j0 + jj];
  float outWreg = outW[j0 + jj];

  {  // transpose x: xT[t*256+b] = xin[b*512+t]; flat g = t*256+b
    int g = bid * 1024 + tid;
    if (g < kT * kB) xT[g] = xin[(g & 255) * kT + (g >> 8)];
  }
  if (bid == 0 && tid < 2 * kB) decacc[tid] = 0.f;

  const float* __restrict__ Wih  = eWih;
  const float* __restrict__ bias = eb;
  float* hc = hA;
  float* hn = hB;

  grid.sync();

  // ---- time loop ----------------------------------------------------------
  for (int step = 0; step < kSteps; ++step) {
    const bool dec = (step >= kT);
    if (step == kT) {   // swap to decoder weights (all waves are between syncs)
#pragma unroll
      for (int lr = 0; lr < ROWS; ++lr)
        Wl[lr * kH + tid] = dWhh[(((lr >> 2) * kH) + j0 + (lr & 3)) * kH + tid];
      Wih  = dWih;
      bias = db;
      __syncthreads();
    }

    // -- GEMM slice: acc[r][q] = sum_{k in slice} W[r][k] * h[k][b0+64q]
    float acc[ROWS][4];
#pragma unroll
    for (int r = 0; r < ROWS; ++r)
#pragma unroll
      for (int q = 0; q < 4; ++q) acc[r][q] = 0.f;

    const int k0 = wv * 64;
    const float2* __restrict__ Wl2 = (const float2*)Wl;
    for (int kk = 0; kk < 64; kk += 2) {
      const int k = k0 + kk;
      const float* __restrict__ hp = hc + k * kB + lane;
      float ha[2][4];
#pragma unroll
      for (int t = 0; t < 2; ++t)
#pragma unroll
        for (int q = 0; q < 4; ++q) ha[t][q] = hp[t * kB + q * 64];
#pragma unroll
      for (int r = 0; r < ROWS; ++r) {
        float2 w2 = Wl2[r * (kH / 2) + (k >> 1)];
#pragma unroll
        for (int q = 0; q < 4; ++q) {
          acc[r][q] = fmaf(w2.x, ha[0][q], acc[r][q]);
          acc[r][q] = fmaf(w2.y, ha[1][q], acc[r][q]);
        }
      }
    }

    // -- combine 16 k-slices (gsum zeroed before entry; ds_add_f32)
#pragma unroll
    for (int r = 0; r < ROWS; ++r)
#pragma unroll
      for (int q = 0; q < 4; ++q)
        atomicAdd(&gsum[r * kB + q * 64 + lane], acc[r][q]);
    __syncthreads();

    // -- cell update: thread (jj, bb)
    float xv;
    if (!dec)            xv = xT[step * kB + bb];
    else if (step == kT) xv = xT[(kT - 1) * kB + bb];
    else                 xv = decin[bb];

    float g4[4];
#pragma unroll
    for (int g = 0; g < 4; ++g) {
      const int grow = g * kH + j0 + jj;            // wave-uniform
      g4[g] = gsum[(g * 4 + jj) * kB + bb] + bias[grow] + xv * Wih[grow];
    }
    float ig = sig_(g4[0]), fg = sig_(g4[1]);
    float gg = tanh_(g4[2]), og = sig_(g4[3]);
    cReg = fg * cReg + ig * gg;
    float hv = og * tanh_(cReg);
    hn[(j0 + jj) * kB + bb] = hv;                   // coalesced

    if (dec) {
      __syncthreads();                 // all gsum reads done before overwrite
      gsum[jj * kB + bb] = hv * outWreg;
      __syncthreads();
      if (tid < kB) {
        float s = gsum[0 * kB + tid] + gsum[1 * kB + tid] +
                  gsum[2 * kB + tid] + gsum[3 * kB + tid];
        atomicAdd(&decacc[(step & 1) * kB + tid], s);
      }
    }

    __syncthreads();                   // all gsum reads done -> re-zero
    ((float4*)gsum)[tid] = make_float4(0.f, 0.f, 0.f, 0.f);

    grid.sync();                       // hn + decacc complete grid-wide

    if (dec) {
      if (bid == 0 && tid < kB) {
        float tot = decacc[(step & 1) * kB + tid] + outb[0];
        out[tid * kP + (step - kT)] = tot;
        decin[tid] = tot;              // autoregressive feedback
        decacc[(step & 1) * kB + tid] = 0.f;   // ready for step+2
      }
      grid.sync();
    }

    float* tmp = hc; hc = hn; hn = tmp;
  }
}

extern "C" void kernel_launch(void* const* d_in, const int* in_sizes, int n_in,
                              void* d_out, int out_size, void* d_ws, size_t ws_size,
                              hipStream_t stream) {
  const float* xin  = (const float*)d_in[0];
  const float* eWih = (const float*)d_in[1];
  const float* eWhh = (const float*)d_in[2];
  const float* eb   = (const float*)d_in[3];
  const float* h0   = (const float*)d_in[4];
  const float* c0   = (const float*)d_in[5];
  const float* dWih = (const float*)d_in[6];
  const float* dWhh = (const float*)d_in[7];
  const float* db   = (const float*)d_in[8];
  const float* outW = (const float*)d_in[9];
  const float* outb = (const float*)d_in[10];
  float* out = (float*)d_out;

  float* wsf    = (float*)d_ws;
  float* hA     = wsf;                         // 1024*256
  float* hB     = hA + kH * kB;                // 1024*256
  float* xT     = hB + kH * kB;                // 512*256
  float* decin  = xT + kT * kB;                // 256
  float* decacc = decin + kB;                  // 2*256

  void* args[] = {(void*)&xin, (void*)&eWih, (void*)&eWhh, (void*)&eb,
                  (void*)&h0, (void*)&c0, (void*)&dWih, (void*)&dWhh,
                  (void*)&db, (void*)&outW, (void*)&outb, (void*)&out,
                  (void*)&hA, (void*)&hB, (void*)&xT, (void*)&decin,
                  (void*)&decacc};
  hipLaunchCooperativeKernel((const void*)lstm2, dim3(256), dim3(1024),
                             args, 0, stream);
}

// Round 5
// 27416.052 us; speedup vs baseline: 3.6359x; 3.2078x over previous
//
#include <hip/hip_runtime.h>

constexpr int kH = 1024;   // hidden
constexpr int kT = 512;    // encoder steps
constexpr int kP = 96;     // decoder steps
constexpr int kB = 256;    // batch
constexpr int kSteps = kT + kP;
constexpr unsigned NB = 256;  // grid size

__device__ __forceinline__ float sig_(float x) { return 1.0f / (1.0f + __expf(-x)); }
__device__ __forceinline__ float tanh_(float x) {
  float e = __expf(-2.0f * fabsf(x));
  float t = (1.0f - e) / (1.0f + e);
  return copysignf(t, x);
}

// Agent-scope relaxed ops: sc-flagged, bypass the non-coherent per-XCD L2,
// coherent at L3. Data path for all cross-block state (h, xT, gpart, decout).
__device__ __forceinline__ float gload(const float* p) {
  return __hip_atomic_load(const_cast<float*>(p), __ATOMIC_RELAXED,
                           __HIP_MEMORY_SCOPE_AGENT);
}
__device__ __forceinline__ void gstore(float* p, float v) {
  __hip_atomic_store(p, v, __ATOMIC_RELAXED, __HIP_MEMORY_SCOPE_AGENT);
}

// Lightweight grid barrier: monotonic counter, no L2 flush. __syncthreads()
// drains each wave's vmcnt (sc1 stores reach the coherence point) before the
// counter bump, so arrival implies this block's data is visible.
__device__ __forceinline__ void gbar(unsigned* cnt, unsigned target) {
  __syncthreads();
  if (threadIdx.x == 0) {
    __hip_atomic_fetch_add(cnt, 1u, __ATOMIC_RELAXED, __HIP_MEMORY_SCOPE_AGENT);
    while (__hip_atomic_load(cnt, __ATOMIC_RELAXED, __HIP_MEMORY_SCOPE_AGENT) < target)
      __builtin_amdgcn_s_sleep(2);
  }
  __syncthreads();
}

__global__ void zero_cnt(unsigned* cnt) { if (threadIdx.x == 0) *cnt = 0u; }

// grid = 256 blocks x 1024 threads (16 waves, 4/SIMD, 1 block/CU).
// Block bid owns hidden units j0..j0+3 (16 gate rows).
// GEMM: wave wv -> (ks = wv&7: k-slice of 128, rg = wv>>3: 8 gate rows),
//       4 batches/thread. Partials to unique LDS slots part[ks][r][b];
//       reader sums ks=0..7 in fixed order -> DETERMINISTIC (no atomics).
// Weights read straight from global (read-only -> plain loads are safe;
// wave-uniform addresses -> scalar path).
__global__ void __launch_bounds__(1024, 4)
lstm4(const float* __restrict__ xin,   // [B][T]
      const float* __restrict__ eWih,  // [4H]
      const float* __restrict__ eWhh,  // [4H][H]
      const float* __restrict__ eb,    // [4H]
      const float* __restrict__ h0,    // [H]
      const float* __restrict__ c0,    // [H]
      const float* __restrict__ dWih,
      const float* __restrict__ dWhh,
      const float* __restrict__ db,
      const float* __restrict__ outW,  // [H]
      const float* __restrict__ outb,  // [1]
      float* __restrict__ out,         // [B][P]
      float* __restrict__ hA,          // ws: hT ping [H][B]
      float* __restrict__ hB,          // ws: hT pong [H][B]
      float* __restrict__ xT,          // ws: [T][B]
      float* __restrict__ gpart,       // ws: [B][256] decoder partials
      float* __restrict__ decout,      // ws: [B] decoder feedback
      unsigned* __restrict__ cnt)      // ws: barrier counter (pre-zeroed)
{
  const int tid  = threadIdx.x;
  const int bid  = blockIdx.x;
  const int j0   = bid * 4;
  const int lane = tid & 63;
  const int wvu  = __builtin_amdgcn_readfirstlane(tid >> 6);
  const int ks   = wvu & 7;          // k-slice 0..7 (128 k each)
  const int rg   = wvu >> 3;         // row-group 0..1 (8 gate rows each)
  const int jj   = tid >> 8;         // update phase: hidden unit 0..3
  const int bb   = tid & 255;        //               batch

  __shared__ float part[8][16][256];   // 128 KB, unique writer per [ks][r]
  __shared__ float decl[4][256];       // 4 KB decoder projection partials
  __shared__ float redw[4];

  // ---- one-time init ------------------------------------------------------
  gstore(&hA[(j0 + jj) * kB + bb], h0[j0 + jj]);
  float cReg    = c0[j0 + jj];
  float outWreg = outW[j0 + jj];
  const float outb0 = outb[0];
  {  // transpose x: xT[t*256+b] = xin[b*512+t]
    int g = bid * 1024 + tid;
    if (g < kT * kB) gstore(&xT[g], xin[(g & 255) * kT + (g >> 8)]);
  }

  // weight row bases for this wave's 8 gate rows (uniform)
  int rowbase[8];
#pragma unroll
  for (int rr = 0; rr < 8; ++rr) {
    int r = rg * 8 + rr;                         // gate-row 0..15
    rowbase[rr] = ((r >> 2) * kH + j0 + (r & 3)) * kH;
  }

  const float* __restrict__ Whh  = eWhh;
  const float* __restrict__ Wih  = eWih;
  const float* __restrict__ bias = eb;
  float* hc = hA;
  float* hn = hB;

  unsigned bt = NB;
  gbar(cnt, bt); bt += NB;

  // ---- time loop ----------------------------------------------------------
  for (int step = 0; step < kSteps; ++step) {
    const bool dec = (step >= kT);
    if (step == kT) { Whh = dWhh; Wih = dWih; bias = db; }

    // decoder: reduce previous step's partials -> y(step-1); fixed tree.
    if (dec && step > kT) {
      float p = 0.0f;
      if (tid < kB) p = gload(&gpart[bid * kB + tid]);   // coalesced
#pragma unroll
      for (int off = 32; off > 0; off >>= 1) p += __shfl_down(p, off, 64);
      if (tid < kB && (tid & 63) == 0) redw[tid >> 6] = p;
      __syncthreads();
      if (tid == 0) {
        float y = ((redw[0] + redw[1]) + redw[2]) + redw[3] + outb0;
        out[bid * kP + (step - 1 - kT)] = y;
        gstore(&decout[bid], y);
      }
    }

    // -- GEMM: acc[rr][q] over k-slice [128ks,128ks+128)
    float acc[8][4];
#pragma unroll
    for (int rr = 0; rr < 8; ++rr)
#pragma unroll
      for (int q = 0; q < 4; ++q) acc[rr][q] = 0.f;

    const int k0 = ks * 128;
    for (int kk = 0; kk < 128; kk += 2) {
      const int k = k0 + kk;
      float2 w2[8];
#pragma unroll
      for (int rr = 0; rr < 8; ++rr)
        w2[rr] = *(const float2*)&Whh[rowbase[rr] + k];   // uniform -> s_load
      float h2[2][4];
#pragma unroll
      for (int dk = 0; dk < 2; ++dk)
#pragma unroll
        for (int q = 0; q < 4; ++q)
          h2[dk][q] = gload(&hc[(k + dk) * kB + q * 64 + lane]);
#pragma unroll
      for (int rr = 0; rr < 8; ++rr)
#pragma unroll
        for (int q = 0; q < 4; ++q) {
          acc[rr][q] = fmaf(w2[rr].x, h2[0][q], acc[rr][q]);
          acc[rr][q] = fmaf(w2[rr].y, h2[1][q], acc[rr][q]);
        }
    }

    // unique-slot partial write (no atomics, conflict-free)
#pragma unroll
    for (int rr = 0; rr < 8; ++rr)
#pragma unroll
      for (int q = 0; q < 4; ++q)
        part[ks][rg * 8 + rr][q * 64 + lane] = acc[rr][q];

    if (dec) { gbar(cnt, bt); bt += NB; }   // decout visible (incl. syncthreads)
    else     { __syncthreads(); }           // part visible

    // -- cell update: thread (jj, bb)
    float xv;
    if (!dec)            xv = gload(&xT[step * kB + bb]);
    else if (step == kT) xv = gload(&xT[(kT - 1) * kB + bb]);
    else                 xv = gload(&decout[bb]);

    float g4[4];
#pragma unroll
    for (int g = 0; g < 4; ++g) {
      const int r = g * 4 + jj;
      float s = part[0][r][bb];
#pragma unroll
      for (int k2 = 1; k2 < 8; ++k2) s += part[k2][r][bb];   // fixed order
      const int grow = g * kH + j0 + jj;                     // wave-uniform
      g4[g] = s + bias[grow] + xv * Wih[grow];
    }
    float ig = sig_(g4[0]), fg = sig_(g4[1]);
    float gg = tanh_(g4[2]), og = sig_(g4[3]);
    cReg = fg * cReg + ig * gg;
    float hv = og * tanh_(cReg);
    gstore(&hn[(j0 + jj) * kB + bb], hv);     // coalesced sc-store

    if (dec) {
      decl[jj][bb] = hv * outWreg;
      __syncthreads();
      if (tid < kB) {
        float s = ((decl[0][tid] + decl[1][tid]) + decl[2][tid]) + decl[3][tid];
        gstore(&gpart[tid * kB + bid], s);    // [b][blk]
      }
    }

    gbar(cnt, bt); bt += NB;                  // h(+gpart) complete grid-wide
    float* tmp = hc; hc = hn; hn = tmp;
  }

  // ---- epilogue: last decoder output (gpart visible after final barrier)
  {
    float p = 0.0f;
    if (tid < kB) p = gload(&gpart[bid * kB + tid]);
#pragma unroll
    for (int off = 32; off > 0; off >>= 1) p += __shfl_down(p, off, 64);
    if (tid < kB && (tid & 63) == 0) redw[tid >> 6] = p;
    __syncthreads();
    if (tid == 0)
      out[bid * kP + (kP - 1)] = ((redw[0] + redw[1]) + redw[2]) + redw[3] + outb0;
  }
}

extern "C" void kernel_launch(void* const* d_in, const int* in_sizes, int n_in,
                              void* d_out, int out_size, void* d_ws, size_t ws_size,
                              hipStream_t stream) {
  const float* xin  = (const float*)d_in[0];
  const float* eWih = (const float*)d_in[1];
  const float* eWhh = (const float*)d_in[2];
  const float* eb   = (const float*)d_in[3];
  const float* h0   = (const float*)d_in[4];
  const float* c0   = (const float*)d_in[5];
  const float* dWih = (const float*)d_in[6];
  const float* dWhh = (const float*)d_in[7];
  const float* db   = (const float*)d_in[8];
  const float* outW = (const float*)d_in[9];
  const float* outb = (const float*)d_in[10];
  float* out = (float*)d_out;

  float* wsf    = (float*)d_ws;
  float* hA     = wsf;                          // 1024*256
  float* hB     = hA + kH * kB;                 // 1024*256
  float* xT     = hB + kH * kB;                 // 512*256
  float* gpart  = xT + kT * kB;                 // 256*256
  float* decout = gpart + kB * 256;             // 256
  unsigned* cnt = (unsigned*)(decout + kB);

  zero_cnt<<<1, 64, 0, stream>>>(cnt);

  void* args[] = {(void*)&xin, (void*)&eWih, (void*)&eWhh, (void*)&eb,
                  (void*)&h0, (void*)&c0, (void*)&dWih, (void*)&dWhh,
                  (void*)&db, (void*)&outW, (void*)&outb, (void*)&out,
                  (void*)&hA, (void*)&hB, (void*)&xT, (void*)&gpart,
                  (void*)&decout, (void*)&cnt};
  hipLaunchCooperativeKernel((const void*)lstm4, dim3(256), dim3(1024),
                             args, 0, stream);
}